// Round 4
// baseline (377.276 us; speedup 1.0000x reference)
//
#include <hip/hip_runtime.h>

typedef __bf16 bf16;
typedef __bf16 bf16x8 __attribute__((ext_vector_type(8)));
typedef float f32x4 __attribute__((ext_vector_type(4)));

#define AS1 __attribute__((address_space(1)))
#define AS3 __attribute__((address_space(3)))

constexpr float kScale  = 7.896444077714954f;                       // 6 * 3^0.25
constexpr float kScaleQ = (float)(7.896444077714954 / 22.627416997969522); // * 512^-0.5

__device__ __forceinline__ void g2l16(const void* g, void* l) {
  __builtin_amdgcn_global_load_lds((const AS1 void*)g, (AS3 void*)l, 16, 0, 0);
}

// ---------------- LayerNorm: fp32 [rows,512] -> bf16 (optionally hi+lo split) ----------------
template <bool SPLIT>
__global__ __launch_bounds__(256) void ln_kernel(
    const float* __restrict__ x, const float* __restrict__ g,
    const float* __restrict__ be, bf16* __restrict__ oh, bf16* __restrict__ ol) {
  int row = blockIdx.x * 4 + (threadIdx.x >> 6);
  int lane = threadIdx.x & 63;
  const float* xr = x + (size_t)row * 512;
  float xa[8];
  *(float4*)&xa[0] = *(const float4*)(xr + lane * 8);
  *(float4*)&xa[4] = *(const float4*)(xr + lane * 8 + 4);
  float s = 0.f, q = 0.f;
#pragma unroll
  for (int i = 0; i < 8; ++i) { s += xa[i]; q += xa[i] * xa[i]; }
#pragma unroll
  for (int off = 32; off; off >>= 1) { s += __shfl_xor(s, off); q += __shfl_xor(q, off); }
  float mean = s * (1.f / 512.f);
  float var = q * (1.f / 512.f) - mean * mean;
  float rstd = rsqrtf(var + 1e-5f);
  float ga[8], ba[8];
  *(float4*)&ga[0] = *(const float4*)(g + lane * 8);
  *(float4*)&ga[4] = *(const float4*)(g + lane * 8 + 4);
  *(float4*)&ba[0] = *(const float4*)(be + lane * 8);
  *(float4*)&ba[4] = *(const float4*)(be + lane * 8 + 4);
  bf16x8 vh, vl;
#pragma unroll
  for (int i = 0; i < 8; ++i) {
    float v = (xa[i] - mean) * rstd * ga[i] + ba[i];
    bf16 h = (bf16)v;
    vh[i] = h;
    if constexpr (SPLIT) vl[i] = (bf16)(v - (float)h);
  }
  *(bf16x8*)(oh + (size_t)row * 512 + lane * 8) = vh;
  if constexpr (SPLIT) *(bf16x8*)(ol + (size_t)row * 512 + lane * 8) = vl;
}

// ------------- transpose + bf16 convert: out[Cc][R] = in[R][Cc]*scale (opt. hi+lo) -------------
template <bool SPLIT>
__global__ __launch_bounds__(256) void transpose_cvt(
    const float* __restrict__ in, bf16* __restrict__ oh, bf16* __restrict__ ol,
    int R, int Cc, long ibs, long obs, float scale) {
  __shared__ float t[32][33];
  int b = blockIdx.z;
  const float* im = in + (size_t)b * ibs;
  int c0 = blockIdx.x * 32, r0 = blockIdx.y * 32;
  int tx = threadIdx.x & 31, ty = threadIdx.x >> 5;
#pragma unroll
  for (int i = 0; i < 4; ++i) {
    int rr = ty + i * 8;
    t[rr][tx] = im[(size_t)(r0 + rr) * Cc + c0 + tx] * scale;
  }
  __syncthreads();
#pragma unroll
  for (int i = 0; i < 4; ++i) {
    int rr = ty + i * 8;
    float v = t[tx][rr];
    bf16 h = (bf16)v;
    size_t oidx = (size_t)b * obs + (size_t)(c0 + rr) * R + r0 + tx;
    oh[oidx] = h;
    if constexpr (SPLIT) ol[oidx] = (bf16)(v - (float)h);
  }
}

// ------------- plain GEMM: C[M,N] = A[M,K] * Bt[N,K]^T, bf16 in, fp32 acc -------------
// MODE 1: out fp32 = acc + bias + res
// MODE 2: out bf16 = relu(acc + bias)
// MODE 3: out fp32 = acc + bias*kScale + res
template <int MODE>
__global__ __launch_bounds__(256) void gemm_bt(
    const bf16* __restrict__ A, const bf16* __restrict__ Bt,
    const float* __restrict__ bias, const float* __restrict__ res,
    float* __restrict__ outf, bf16* __restrict__ outb, int N, int K) {
  __shared__ bf16 lA[128 * 64], lB[128 * 64];
  int tid = threadIdx.x;
  int lane = tid & 63, w = tid >> 6;
  int wr = w >> 1, wc = w & 1, gq = lane >> 4, r = lane & 15;
  int m0 = blockIdx.x * 128, n0 = blockIdx.y * 128;
  size_t Kb = (size_t)K * 2;
  const char* Ab = (const char*)A + (size_t)m0 * Kb;
  const char* Bb = (const char*)Bt + (size_t)n0 * Kb;
  f32x4 acc[4][4] = {};
  int srow = lane >> 3, sslot = lane & 7;
  for (int kt = 0; kt < K; kt += 64) {
#pragma unroll
    for (int i = 0; i < 4; ++i) {
      int chunk = i * 4 + w;
      int row = chunk * 8 + srow;
      int slot = sslot ^ (row & 7);
      g2l16(Ab + (size_t)row * Kb + kt * 2 + slot * 16, (char*)lA + chunk * 1024);
      g2l16(Bb + (size_t)row * Kb + kt * 2 + slot * 16, (char*)lB + chunk * 1024);
    }
    __syncthreads();
    bf16x8 af[4][2], bfr[4][2];
#pragma unroll
    for (int f = 0; f < 4; ++f)
#pragma unroll
      for (int ks = 0; ks < 2; ++ks) {
        int ra = wr * 64 + f * 16 + r;
        af[f][ks] = *(const bf16x8*)((const char*)lA + ra * 128 + (((ks * 4 + gq) ^ (ra & 7)) * 16));
        int rb = wc * 64 + f * 16 + r;
        bfr[f][ks] = *(const bf16x8*)((const char*)lB + rb * 128 + (((ks * 4 + gq) ^ (rb & 7)) * 16));
      }
#pragma unroll
    for (int fm = 0; fm < 4; ++fm)
#pragma unroll
      for (int fn = 0; fn < 4; ++fn)
#pragma unroll
        for (int ks = 0; ks < 2; ++ks)
          acc[fm][fn] = __builtin_amdgcn_mfma_f32_16x16x32_bf16(af[fm][ks], bfr[fn][ks], acc[fm][fn], 0, 0, 0);
    __syncthreads();
  }
#pragma unroll
  for (int fm = 0; fm < 4; ++fm)
#pragma unroll
    for (int fn = 0; fn < 4; ++fn)
#pragma unroll
      for (int rg = 0; rg < 4; ++rg) {
        int row = m0 + wr * 64 + fm * 16 + gq * 4 + rg;
        int col = n0 + wc * 64 + fn * 16 + r;
        float v = acc[fm][fn][rg];
        if constexpr (MODE == 1) {
          outf[(size_t)row * N + col] = v + bias[col] + res[(size_t)row * N + col];
        } else if constexpr (MODE == 2) {
          outb[(size_t)row * N + col] = (bf16)fmaxf(v + bias[col], 0.f);
        } else {
          outf[(size_t)row * N + col] = v + bias[col] * kScale + res[(size_t)row * N + col];
        }
      }
}

// ------------- split-precision QKV GEMM: (Ah+Al)[8192,512] x (Bh+Bl)[1536,512]^T -------------
// scatter: q,k -> hi/lo bf16 [B,H,T,64]; v -> bf16 [B,H,D,T]
__global__ __launch_bounds__(256) void gemm_qkv(
    const bf16* __restrict__ Ah, const bf16* __restrict__ Al,
    const bf16* __restrict__ Bh, const bf16* __restrict__ Bl,
    bf16* __restrict__ qh, bf16* __restrict__ ql,
    bf16* __restrict__ kh, bf16* __restrict__ kl, bf16* __restrict__ vo) {
  __shared__ bf16 lAh[128 * 64], lAl[128 * 64], lBh[128 * 64], lBl[128 * 64];
  const int K = 512;
  int tid = threadIdx.x;
  int lane = tid & 63, w = tid >> 6;
  int wr = w >> 1, wc = w & 1, gq = lane >> 4, r = lane & 15;
  int m0 = blockIdx.x * 128, n0 = blockIdx.y * 128;
  size_t Kb = (size_t)K * 2;
  const char* Ahb = (const char*)Ah + (size_t)m0 * Kb;
  const char* Alb = (const char*)Al + (size_t)m0 * Kb;
  const char* Bhb = (const char*)Bh + (size_t)n0 * Kb;
  const char* Blb = (const char*)Bl + (size_t)n0 * Kb;
  f32x4 acc[4][4] = {};
  int srow = lane >> 3, sslot = lane & 7;
  for (int kt = 0; kt < K; kt += 64) {
#pragma unroll
    for (int i = 0; i < 4; ++i) {
      int chunk = i * 4 + w;
      int row = chunk * 8 + srow;
      int slot = sslot ^ (row & 7);
      size_t go = (size_t)row * Kb + kt * 2 + slot * 16;
      g2l16(Ahb + go, (char*)lAh + chunk * 1024);
      g2l16(Alb + go, (char*)lAl + chunk * 1024);
      g2l16(Bhb + go, (char*)lBh + chunk * 1024);
      g2l16(Blb + go, (char*)lBl + chunk * 1024);
    }
    __syncthreads();
#pragma unroll
    for (int ks = 0; ks < 2; ++ks) {
      bf16x8 ah[4], al[4], bh[4], bl[4];
#pragma unroll
      for (int f = 0; f < 4; ++f) {
        int ra = wr * 64 + f * 16 + r;
        int offa = ra * 128 + (((ks * 4 + gq) ^ (ra & 7)) * 16);
        ah[f] = *(const bf16x8*)((const char*)lAh + offa);
        al[f] = *(const bf16x8*)((const char*)lAl + offa);
        int rb = wc * 64 + f * 16 + r;
        int offb = rb * 128 + (((ks * 4 + gq) ^ (rb & 7)) * 16);
        bh[f] = *(const bf16x8*)((const char*)lBh + offb);
        bl[f] = *(const bf16x8*)((const char*)lBl + offb);
      }
#pragma unroll
      for (int fm = 0; fm < 4; ++fm)
#pragma unroll
        for (int fn = 0; fn < 4; ++fn) {
          acc[fm][fn] = __builtin_amdgcn_mfma_f32_16x16x32_bf16(ah[fm], bh[fn], acc[fm][fn], 0, 0, 0);
          acc[fm][fn] = __builtin_amdgcn_mfma_f32_16x16x32_bf16(ah[fm], bl[fn], acc[fm][fn], 0, 0, 0);
          acc[fm][fn] = __builtin_amdgcn_mfma_f32_16x16x32_bf16(al[fm], bh[fn], acc[fm][fn], 0, 0, 0);
        }
    }
    __syncthreads();
  }
#pragma unroll
  for (int fm = 0; fm < 4; ++fm)
#pragma unroll
    for (int fn = 0; fn < 4; ++fn)
#pragma unroll
      for (int rg = 0; rg < 4; ++rg) {
        int row = m0 + wr * 64 + fm * 16 + gq * 4 + rg;
        int col = n0 + wc * 64 + fn * 16 + r;
        float v = acc[fm][fn][rg];
        int bb = row >> 11, t = row & 2047;
        int which = col >> 9, hd = col & 511, hh = hd >> 6, d = hd & 63;
        size_t bhh = (size_t)bb * 8 + hh;
        if (which == 0) {
          size_t idx = (bhh * 2048 + t) * 64 + d;
          bf16 h = (bf16)v;
          qh[idx] = h; ql[idx] = (bf16)(v - (float)h);
        } else if (which == 1) {
          size_t idx = (bhh * 2048 + t) * 64 + d;
          bf16 h = (bf16)v;
          kh[idx] = h; kl[idx] = (bf16)(v - (float)h);
        } else {
          vo[(bhh * 64 + d) * 2048 + t] = (bf16)v;
        }
      }
}

// ------------- causal flash attention; q,k hi/lo:[B,H,T,64], v^T:[B,H,64,T] -------------
// Barrier-free: K/V fragments loaded directly from global (L2-resident per head);
// only the per-wave P tile goes through LDS. 4 waves x 16 q-rows, KV tiles of 64.
__global__ __launch_bounds__(256, 4) void attn_kernel(
    const bf16* __restrict__ Qh, const bf16* __restrict__ Ql,
    const bf16* __restrict__ Kh, const bf16* __restrict__ Kl,
    const bf16* __restrict__ Vt, bf16* __restrict__ out) {
  __shared__ bf16 lP[4][16 * 72];
  int tid = threadIdx.x, lane = tid & 63, w = tid >> 6;
  int gq = lane >> 4, r = lane & 15;
  int bh = blockIdx.x;            // 0..31
  int qt = 31 - (int)blockIdx.y;  // heavy tiles dispatched first
  const char* Qhb = (const char*)(Qh + (size_t)bh * 2048 * 64);
  const char* Qlb = (const char*)(Ql + (size_t)bh * 2048 * 64);
  const char* Khb = (const char*)(Kh + (size_t)bh * 2048 * 64);
  const char* Klb = (const char*)(Kl + (size_t)bh * 2048 * 64);
  const char* Vb  = (const char*)(Vt + (size_t)bh * 64 * 2048);
  int q0 = qt * 64 + w * 16;
  bf16x8 qfh[2], qfl[2];
#pragma unroll
  for (int ks = 0; ks < 2; ++ks) {
    size_t qoff = (size_t)(q0 + r) * 128 + ks * 64 + gq * 16;
    qfh[ks] = *(const bf16x8*)(Qhb + qoff);
    qfl[ks] = *(const bf16x8*)(Qlb + qoff);
  }
  f32x4 O[4] = {};
  float mrun[4], lrun[4];
#pragma unroll
  for (int rg = 0; rg < 4; ++rg) { mrun[rg] = -1e30f; lrun[rg] = 0.f; }
  int nkv = qt + 1;
  for (int kv = 0; kv < nkv; ++kv) {
    int j0 = kv * 64;
    f32x4 s[4] = {};
#pragma unroll
    for (int ks = 0; ks < 2; ++ks) {
      bf16x8 khf[4], klf[4];
#pragma unroll
      for (int fc = 0; fc < 4; ++fc) {
        size_t off = ((size_t)(j0 + fc * 16 + r) * 64 + ks * 32 + gq * 8) * 2;
        khf[fc] = *(const bf16x8*)(Khb + off);
        klf[fc] = *(const bf16x8*)(Klb + off);
      }
#pragma unroll
      for (int fc = 0; fc < 4; ++fc) {
        s[fc] = __builtin_amdgcn_mfma_f32_16x16x32_bf16(qfh[ks], khf[fc], s[fc], 0, 0, 0);
        s[fc] = __builtin_amdgcn_mfma_f32_16x16x32_bf16(qfh[ks], klf[fc], s[fc], 0, 0, 0);
        s[fc] = __builtin_amdgcn_mfma_f32_16x16x32_bf16(qfl[ks], khf[fc], s[fc], 0, 0, 0);
      }
    }
    if (j0 + 63 > q0) {
#pragma unroll
      for (int fc = 0; fc < 4; ++fc)
#pragma unroll
        for (int rg = 0; rg < 4; ++rg) {
          int t = q0 + gq * 4 + rg;
          int j = j0 + fc * 16 + r;
          if (j > t) s[fc][rg] = -1e30f;
        }
    }
#pragma unroll
    for (int rg = 0; rg < 4; ++rg) {
      float v = fmaxf(fmaxf(s[0][rg], s[1][rg]), fmaxf(s[2][rg], s[3][rg]));
      v = fmaxf(v, __shfl_xor(v, 1));
      v = fmaxf(v, __shfl_xor(v, 2));
      v = fmaxf(v, __shfl_xor(v, 4));
      v = fmaxf(v, __shfl_xor(v, 8));
      float mo = mrun[rg];
      float mn = fmaxf(mo, v);
      if (mn - mo > 8.f) {  // defer-max: only rescale on significant growth
        float sc = __expf(mo - mn);
        lrun[rg] *= sc;
#pragma unroll
        for (int fd = 0; fd < 4; ++fd) O[fd][rg] *= sc;
        mrun[rg] = mn;
      } else {
        mn = mo;
      }
      float ps = 0.f;
      int prow = gq * 4 + rg;
#pragma unroll
      for (int fc = 0; fc < 4; ++fc) {
        float p = __expf(s[fc][rg] - mn);
        ps += p;
        lP[w][prow * 72 + fc * 16 + r] = (bf16)p;
      }
      ps += __shfl_xor(ps, 1);
      ps += __shfl_xor(ps, 2);
      ps += __shfl_xor(ps, 4);
      ps += __shfl_xor(ps, 8);
      lrun[rg] += ps;
    }
    bf16x8 vf[4][2], pf[2];
#pragma unroll
    for (int fd = 0; fd < 4; ++fd)
#pragma unroll
      for (int ks = 0; ks < 2; ++ks)
        vf[fd][ks] = *(const bf16x8*)(Vb + ((size_t)(fd * 16 + r) * 2048 + j0 + ks * 32 + gq * 8) * 2);
#pragma unroll
    for (int ks = 0; ks < 2; ++ks)
      pf[ks] = *(const bf16x8*)((const char*)&lP[w][0] + r * 144 + ks * 64 + gq * 16);
#pragma unroll
    for (int fd = 0; fd < 4; ++fd)
#pragma unroll
      for (int ks = 0; ks < 2; ++ks)
        O[fd] = __builtin_amdgcn_mfma_f32_16x16x32_bf16(pf[ks], vf[fd][ks], O[fd], 0, 0, 0);
  }
  int bb = bh >> 3, hh = bh & 7;
#pragma unroll
  for (int fd = 0; fd < 4; ++fd)
#pragma unroll
    for (int rg = 0; rg < 4; ++rg) {
      int t = q0 + gq * 4 + rg;
      int d = fd * 16 + r;
      out[((size_t)bb * 2048 + t) * 512 + hh * 64 + d] =
          (bf16)(O[fd][rg] / lrun[rg]);
    }
}

extern "C" void kernel_launch(void* const* d_in, const int* in_sizes, int n_in,
                              void* d_out, int out_size, void* d_ws, size_t ws_size,
                              hipStream_t stream) {
  (void)in_sizes; (void)n_in; (void)out_size; (void)ws_size;
  const float* x      = (const float*)d_in[0];
  const float* wq     = (const float*)d_in[1];
  const float* wk     = (const float*)d_in[2];
  const float* wv     = (const float*)d_in[3];
  const float* w_proj = (const float*)d_in[4];
  const float* b_proj = (const float*)d_in[5];
  const float* w1     = (const float*)d_in[6];
  const float* b1     = (const float*)d_in[7];
  const float* w2     = (const float*)d_in[8];
  const float* b2     = (const float*)d_in[9];
  const float* g1     = (const float*)d_in[10];
  const float* be1    = (const float*)d_in[11];
  const float* g2     = (const float*)d_in[12];
  const float* be2    = (const float*)d_in[13];
  float* outp = (float*)d_out;

  char* ws = (char*)d_ws;
  size_t off = 0;
  auto alloc = [&](size_t bytes) {
    char* p = ws + off;
    off += (bytes + 255) & ~(size_t)255;
    return p;
  };
  const size_t MC2 = (size_t)8192 * 512 * 2;   // 8.4 MB
  bf16* xh  = (bf16*)alloc(MC2);               // also attn output later
  bf16* xl  = (bf16*)alloc(MC2);               // also x1_ln later
  bf16* qhb = (bf16*)alloc(MC2);               // qh..kl+vb region also hbuf later
  bf16* qlb = (bf16*)alloc(MC2);
  bf16* khb = (bf16*)alloc(MC2);
  bf16* klb = (bf16*)alloc(MC2);
  bf16* vb  = (bf16*)alloc(MC2);
  float* x1 = (float*)alloc((size_t)8192 * 512 * 4);
  bf16* Wqkvh = (bf16*)alloc((size_t)1536 * 512 * 2);
  bf16* Wqkvl = (bf16*)alloc((size_t)1536 * 512 * 2);
  bf16* Wp    = (bf16*)alloc((size_t)512 * 512 * 2);
  bf16* W1t   = (bf16*)alloc((size_t)2048 * 512 * 2);
  bf16* W2t   = (bf16*)alloc((size_t)512 * 2048 * 2);
  bf16* attn  = xh;
  bf16* x1_ln = xl;
  bf16* hbuf  = qhb;  // spans qhb..klb (33.6 MB needed, 4 x 8.4 MB available)

  // weights -> bf16 (hi/lo for qkv), transposed to [N][K]; scales folded
  transpose_cvt<true><<<dim3(2, 16, 8), 256, 0, stream>>>(wq, Wqkvh,                 Wqkvl,                 512, 64, 512 * 64, 64 * 512, kScaleQ);
  transpose_cvt<true><<<dim3(2, 16, 8), 256, 0, stream>>>(wk, Wqkvh + 512 * 512,     Wqkvl + 512 * 512,     512, 64, 512 * 64, 64 * 512, kScale);
  transpose_cvt<true><<<dim3(2, 16, 8), 256, 0, stream>>>(wv, Wqkvh + 2 * 512 * 512, Wqkvl + 2 * 512 * 512, 512, 64, 512 * 64, 64 * 512, kScale);
  transpose_cvt<false><<<dim3(16, 16, 1), 256, 0, stream>>>(w_proj, Wp, nullptr, 512, 512, 0, 0, 1.f);
  transpose_cvt<false><<<dim3(64, 16, 1), 256, 0, stream>>>(w1, W1t, nullptr, 512, 2048, 0, 0, 1.f);
  transpose_cvt<false><<<dim3(16, 64, 1), 256, 0, stream>>>(w2, W2t, nullptr, 2048, 512, 0, 0, kScale);

  ln_kernel<true><<<2048, 256, 0, stream>>>(x, g1, be1, xh, xl);
  gemm_qkv<<<dim3(64, 12), 256, 0, stream>>>(xh, xl, Wqkvh, Wqkvl, qhb, qlb, khb, klb, vb);
  attn_kernel<<<dim3(32, 32), 256, 0, stream>>>(qhb, qlb, khb, klb, vb, attn);
  gemm_bt<1><<<dim3(64, 4), 256, 0, stream>>>(attn, Wp, b_proj, x, x1, nullptr, 512, 512);
  ln_kernel<false><<<2048, 256, 0, stream>>>(x1, g2, be2, x1_ln, nullptr);
  gemm_bt<2><<<dim3(64, 16), 256, 0, stream>>>(x1_ln, W1t, b1, nullptr, nullptr, hbuf, 2048, 512);
  gemm_bt<3><<<dim3(64, 4), 256, 0, stream>>>(hbuf, W2t, b2, x1, outp, nullptr, 512, 2048);
}

// Round 5
// 213.484 us; speedup vs baseline: 1.7672x; 1.7672x over previous
//
#include <hip/hip_runtime.h>

typedef _Float16 f16;
typedef f16 f16x8 __attribute__((ext_vector_type(8)));
typedef float f32x4 __attribute__((ext_vector_type(4)));

#define AS1 __attribute__((address_space(1)))
#define AS3 __attribute__((address_space(3)))

constexpr float kScale  = 7.896444077714954f;                       // 6 * 3^0.25
constexpr float kScaleQ = (float)(7.896444077714954 / 22.627416997969522); // * 512^-0.5

__device__ __forceinline__ void g2l16(const void* g, void* l) {
  __builtin_amdgcn_global_load_lds((const AS1 void*)g, (AS3 void*)l, 16, 0, 0);
}

// ---------------- LayerNorm: fp32 [rows,512] -> f16 ----------------
__global__ __launch_bounds__(256) void ln_kernel(
    const float* __restrict__ x, const float* __restrict__ g,
    const float* __restrict__ be, f16* __restrict__ out) {
  int row = blockIdx.x * 4 + (threadIdx.x >> 6);
  int lane = threadIdx.x & 63;
  const float* xr = x + (size_t)row * 512;
  float xa[8];
  *(float4*)&xa[0] = *(const float4*)(xr + lane * 8);
  *(float4*)&xa[4] = *(const float4*)(xr + lane * 8 + 4);
  float s = 0.f, q = 0.f;
#pragma unroll
  for (int i = 0; i < 8; ++i) { s += xa[i]; q += xa[i] * xa[i]; }
#pragma unroll
  for (int off = 32; off; off >>= 1) { s += __shfl_xor(s, off); q += __shfl_xor(q, off); }
  float mean = s * (1.f / 512.f);
  float var = q * (1.f / 512.f) - mean * mean;
  float rstd = rsqrtf(var + 1e-5f);
  float ga[8], ba[8];
  *(float4*)&ga[0] = *(const float4*)(g + lane * 8);
  *(float4*)&ga[4] = *(const float4*)(g + lane * 8 + 4);
  *(float4*)&ba[0] = *(const float4*)(be + lane * 8);
  *(float4*)&ba[4] = *(const float4*)(be + lane * 8 + 4);
  f16x8 o;
#pragma unroll
  for (int i = 0; i < 8; ++i) o[i] = (f16)((xa[i] - mean) * rstd * ga[i] + ba[i]);
  *(f16x8*)(out + (size_t)row * 512 + lane * 8) = o;
}

// ------------- transpose + f16 convert: out[Cc][R] = in[R][Cc]*scale -------------
__global__ __launch_bounds__(256) void transpose_cvt(
    const float* __restrict__ in, f16* __restrict__ out,
    int R, int Cc, long ibs, long obs, float scale) {
  __shared__ float t[32][33];
  int b = blockIdx.z;
  const float* im = in + (size_t)b * ibs;
  int c0 = blockIdx.x * 32, r0 = blockIdx.y * 32;
  int tx = threadIdx.x & 31, ty = threadIdx.x >> 5;
#pragma unroll
  for (int i = 0; i < 4; ++i) {
    int rr = ty + i * 8;
    t[rr][tx] = im[(size_t)(r0 + rr) * Cc + c0 + tx] * scale;
  }
  __syncthreads();
#pragma unroll
  for (int i = 0; i < 4; ++i) {
    int rr = ty + i * 8;
    out[(size_t)b * obs + (size_t)(c0 + rr) * R + r0 + tx] = (f16)t[tx][rr];
  }
}

// ------------- GEMM: C[M,N] = A[M,K] * Bt[N,K]^T, f16 in, fp32 acc -------------
// MODE 0: qkv scatter (q,k -> [B,H,T,64]; v -> [B,H,D,T])
// MODE 1: out fp32 = acc + bias + res
// MODE 2: out f16  = relu(acc + bias)
// MODE 3: out fp32 = acc + bias*kScale + res
template <int MODE>
__global__ __launch_bounds__(256) void gemm_bt(
    const f16* __restrict__ A, const f16* __restrict__ Bt,
    const float* __restrict__ bias, const float* __restrict__ res,
    float* __restrict__ outf, f16* __restrict__ outb,
    f16* __restrict__ qo, f16* __restrict__ ko, f16* __restrict__ vo,
    int N, int K) {
  __shared__ f16 lA[128 * 64], lB[128 * 64];
  int tid = threadIdx.x;
  int lane = tid & 63, w = tid >> 6;
  int wr = w >> 1, wc = w & 1, gq = lane >> 4, r = lane & 15;
  int m0 = blockIdx.x * 128, n0 = blockIdx.y * 128;
  size_t Kb = (size_t)K * 2;
  const char* Ab = (const char*)A + (size_t)m0 * Kb;
  const char* Bb = (const char*)Bt + (size_t)n0 * Kb;
  f32x4 acc[4][4] = {};
  int srow = lane >> 3, sslot = lane & 7;
  for (int kt = 0; kt < K; kt += 64) {
#pragma unroll
    for (int i = 0; i < 4; ++i) {
      int chunk = i * 4 + w;
      int row = chunk * 8 + srow;
      int slot = sslot ^ (row & 7);
      g2l16(Ab + (size_t)row * Kb + kt * 2 + slot * 16, (char*)lA + chunk * 1024);
      g2l16(Bb + (size_t)row * Kb + kt * 2 + slot * 16, (char*)lB + chunk * 1024);
    }
    __syncthreads();
    f16x8 af[4][2], bfr[4][2];
#pragma unroll
    for (int f = 0; f < 4; ++f)
#pragma unroll
      for (int ks = 0; ks < 2; ++ks) {
        int ra = wr * 64 + f * 16 + r;
        af[f][ks] = *(const f16x8*)((const char*)lA + ra * 128 + (((ks * 4 + gq) ^ (ra & 7)) * 16));
        int rb = wc * 64 + f * 16 + r;
        bfr[f][ks] = *(const f16x8*)((const char*)lB + rb * 128 + (((ks * 4 + gq) ^ (rb & 7)) * 16));
      }
#pragma unroll
    for (int fm = 0; fm < 4; ++fm)
#pragma unroll
      for (int fn = 0; fn < 4; ++fn)
#pragma unroll
        for (int ks = 0; ks < 2; ++ks)
          acc[fm][fn] = __builtin_amdgcn_mfma_f32_16x16x32_f16(af[fm][ks], bfr[fn][ks], acc[fm][fn], 0, 0, 0);
    __syncthreads();
  }
#pragma unroll
  for (int fm = 0; fm < 4; ++fm)
#pragma unroll
    for (int fn = 0; fn < 4; ++fn)
#pragma unroll
      for (int rg = 0; rg < 4; ++rg) {
        int row = m0 + wr * 64 + fm * 16 + gq * 4 + rg;
        int col = n0 + wc * 64 + fn * 16 + r;
        float v = acc[fm][fn][rg];
        if constexpr (MODE == 1) {
          outf[(size_t)row * N + col] = v + bias[col] + res[(size_t)row * N + col];
        } else if constexpr (MODE == 2) {
          outb[(size_t)row * N + col] = (f16)fmaxf(v + bias[col], 0.f);
        } else if constexpr (MODE == 3) {
          outf[(size_t)row * N + col] = v + bias[col] * kScale + res[(size_t)row * N + col];
        } else {
          int bb = row >> 11, t = row & 2047;
          int which = col >> 9, hd = col & 511, hh = hd >> 6, d = hd & 63;
          size_t bh = (size_t)bb * 8 + hh;
          if (which == 0)      qo[(bh * 2048 + t) * 64 + d] = (f16)v;
          else if (which == 1) ko[(bh * 2048 + t) * 64 + d] = (f16)v;
          else                 vo[(bh * 64 + d) * 2048 + t] = (f16)v;
        }
      }
}

// ------------- causal flash attention, paired q-tiles for balance -------------
// q,k:[B,H,T,64], v^T:[B,H,64,T]. Block (bh, p) handles q-tiles A=p and B=31-p
// (64 rows each; 4 waves x 16 rows per tile). Every block: exactly 33 tile-iters.
// K/V staging and K/V fragments are shared between the two tiles.
__global__ __launch_bounds__(256) void attn_kernel(
    const f16* __restrict__ Q, const f16* __restrict__ K,
    const f16* __restrict__ Vt, f16* __restrict__ out) {
  __shared__ f16 lK[64 * 64], lV[64 * 64];
  __shared__ f16 lP[4][16 * 72];
  int tid = threadIdx.x, lane = tid & 63, w = tid >> 6;
  int gq = lane >> 4, r = lane & 15;
  int bh = blockIdx.x;   // 0..31
  int p = blockIdx.y;    // 0..15 -> tiles p and 31-p
  const char* Qb = (const char*)(Q + (size_t)bh * 2048 * 64);
  const char* Kb = (const char*)(K + (size_t)bh * 2048 * 64);
  const char* Vb = (const char*)(Vt + (size_t)bh * 64 * 2048);
  int q0A = p * 64 + w * 16;
  int q0B = (31 - p) * 64 + w * 16;
  f16x8 qfA[2], qfB[2];
#pragma unroll
  for (int ks = 0; ks < 2; ++ks) {
    qfA[ks] = *(const f16x8*)(Qb + (size_t)(q0A + r) * 128 + ks * 64 + gq * 16);
    qfB[ks] = *(const f16x8*)(Qb + (size_t)(q0B + r) * 128 + ks * 64 + gq * 16);
  }
  f32x4 OA[4] = {}, OB[4] = {};
  float mA[4], lA_[4], mB[4], lB_[4];
#pragma unroll
  for (int rg = 0; rg < 4; ++rg) { mA[rg] = mB[rg] = -1e30f; lA_[rg] = lB_[rg] = 0.f; }
  int srow = lane >> 3, sslot = lane & 7;

  f16x8 vf[4][2];
  auto smpv = [&](f32x4 (&s)[4], float (&m)[4], float (&l)[4], f32x4 (&O)[4]) {
#pragma unroll
    for (int rg = 0; rg < 4; ++rg) {
      float v = fmaxf(fmaxf(s[0][rg], s[1][rg]), fmaxf(s[2][rg], s[3][rg]));
      v = fmaxf(v, __shfl_xor(v, 1));
      v = fmaxf(v, __shfl_xor(v, 2));
      v = fmaxf(v, __shfl_xor(v, 4));
      v = fmaxf(v, __shfl_xor(v, 8));
      float mo = m[rg];
      float mn = fmaxf(mo, v);
      if (mn - mo > 8.f) {  // defer-max
        float sc = __expf(mo - mn);
        l[rg] *= sc;
#pragma unroll
        for (int fd = 0; fd < 4; ++fd) O[fd][rg] *= sc;
        m[rg] = mn;
      } else {
        mn = mo;
      }
      float ps = 0.f;
      int prow = gq * 4 + rg;
#pragma unroll
      for (int fc = 0; fc < 4; ++fc) {
        float pe = __expf(s[fc][rg] - mn);
        ps += pe;
        lP[w][prow * 72 + fc * 16 + r] = (f16)pe;
      }
      ps += __shfl_xor(ps, 1);
      ps += __shfl_xor(ps, 2);
      ps += __shfl_xor(ps, 4);
      ps += __shfl_xor(ps, 8);
      l[rg] += ps;
    }
    f16x8 pf[2];
#pragma unroll
    for (int ks = 0; ks < 2; ++ks)
      pf[ks] = *(const f16x8*)((const char*)&lP[w][0] + r * 144 + ks * 64 + gq * 16);
#pragma unroll
    for (int fd = 0; fd < 4; ++fd)
#pragma unroll
      for (int ks = 0; ks < 2; ++ks)
        O[fd] = __builtin_amdgcn_mfma_f32_16x16x32_f16(pf[ks], vf[fd][ks], O[fd], 0, 0, 0);
  };

  int nkv = 32 - p;
  for (int kv = 0; kv < nkv; ++kv) {
    int j0 = kv * 64;
#pragma unroll
    for (int i = 0; i < 2; ++i) {
      int chunk = i * 4 + w;
      int row = chunk * 8 + srow;
      int slot = sslot ^ (row & 7);
      g2l16(Kb + (size_t)(j0 + row) * 128 + slot * 16, (char*)lK + chunk * 1024);
      g2l16(Vb + (size_t)row * 4096 + j0 * 2 + slot * 16, (char*)lV + chunk * 1024);
    }
    __syncthreads();
    f16x8 kf[4][2];
#pragma unroll
    for (int fc = 0; fc < 4; ++fc)
#pragma unroll
      for (int ks = 0; ks < 2; ++ks) {
        int rj = fc * 16 + r;
        kf[fc][ks] = *(const f16x8*)((const char*)lK + rj * 128 + (((ks * 4 + gq) ^ (rj & 7)) * 16));
      }
#pragma unroll
    for (int fd = 0; fd < 4; ++fd)
#pragma unroll
      for (int ks = 0; ks < 2; ++ks) {
        int rd = fd * 16 + r;
        vf[fd][ks] = *(const f16x8*)((const char*)lV + rd * 128 + (((ks * 4 + gq) ^ (rd & 7)) * 16));
      }
    bool actA = (kv <= p);
    f32x4 sB[4] = {};
#pragma unroll
    for (int ks = 0; ks < 2; ++ks)
#pragma unroll
      for (int fc = 0; fc < 4; ++fc)
        sB[fc] = __builtin_amdgcn_mfma_f32_16x16x32_f16(qfB[ks], kf[fc][ks], sB[fc], 0, 0, 0);
    if (kv == nkv - 1) {  // diagonal tile for B
#pragma unroll
      for (int fc = 0; fc < 4; ++fc)
#pragma unroll
        for (int rg = 0; rg < 4; ++rg) {
          int t = q0B + gq * 4 + rg;
          int j = j0 + fc * 16 + r;
          if (j > t) sB[fc][rg] = -1e30f;
        }
    }
    smpv(sB, mB, lB_, OB);
    if (actA) {
      f32x4 sA[4] = {};
#pragma unroll
      for (int ks = 0; ks < 2; ++ks)
#pragma unroll
        for (int fc = 0; fc < 4; ++fc)
          sA[fc] = __builtin_amdgcn_mfma_f32_16x16x32_f16(qfA[ks], kf[fc][ks], sA[fc], 0, 0, 0);
      if (kv == p) {  // diagonal tile for A
#pragma unroll
        for (int fc = 0; fc < 4; ++fc)
#pragma unroll
          for (int rg = 0; rg < 4; ++rg) {
            int t = q0A + gq * 4 + rg;
            int j = j0 + fc * 16 + r;
            if (j > t) sA[fc][rg] = -1e30f;
          }
      }
      smpv(sA, mA, lA_, OA);
    }
    __syncthreads();
  }
  int bb = bh >> 3, hh = bh & 7;
#pragma unroll
  for (int fd = 0; fd < 4; ++fd)
#pragma unroll
    for (int rg = 0; rg < 4; ++rg) {
      int d = fd * 16 + r;
      int tA = q0A + gq * 4 + rg;
      int tB = q0B + gq * 4 + rg;
      out[((size_t)bb * 2048 + tA) * 512 + hh * 64 + d] = (f16)(OA[fd][rg] / lA_[rg]);
      out[((size_t)bb * 2048 + tB) * 512 + hh * 64 + d] = (f16)(OB[fd][rg] / lB_[rg]);
    }
}

extern "C" void kernel_launch(void* const* d_in, const int* in_sizes, int n_in,
                              void* d_out, int out_size, void* d_ws, size_t ws_size,
                              hipStream_t stream) {
  (void)in_sizes; (void)n_in; (void)out_size; (void)ws_size;
  const float* x      = (const float*)d_in[0];
  const float* wq     = (const float*)d_in[1];
  const float* wk     = (const float*)d_in[2];
  const float* wv     = (const float*)d_in[3];
  const float* w_proj = (const float*)d_in[4];
  const float* b_proj = (const float*)d_in[5];
  const float* w1     = (const float*)d_in[6];
  const float* b1     = (const float*)d_in[7];
  const float* w2     = (const float*)d_in[8];
  const float* b2     = (const float*)d_in[9];
  const float* g1     = (const float*)d_in[10];
  const float* be1    = (const float*)d_in[11];
  const float* g2     = (const float*)d_in[12];
  const float* be2    = (const float*)d_in[13];
  float* outp = (float*)d_out;

  char* ws = (char*)d_ws;
  size_t off = 0;
  auto alloc = [&](size_t bytes) {
    char* p = ws + off;
    off += (bytes + 255) & ~(size_t)255;
    return p;
  };
  const size_t MC2 = (size_t)8192 * 512 * 2;   // 8.4 MB
  f16* x_ln  = (f16*)alloc(MC2);
  f16* qb    = (f16*)alloc(MC2);   // qb..attn (33.6 MB) reused as hbuf later
  f16* kb    = (f16*)alloc(MC2);
  f16* vb    = (f16*)alloc(MC2);
  f16* attn  = (f16*)alloc(MC2);
  float* x1  = (float*)alloc((size_t)8192 * 512 * 4);
  f16* Wqkv  = (f16*)alloc((size_t)1536 * 512 * 2);
  f16* Wp    = (f16*)alloc((size_t)512 * 512 * 2);
  f16* W1t   = (f16*)alloc((size_t)2048 * 512 * 2);
  f16* W2t   = (f16*)alloc((size_t)512 * 2048 * 2);
  f16* x1_ln = x_ln;
  f16* hbuf  = qb;  // 32 MB spans qb..attn

  // weights -> f16, transposed to [N][K]; scales folded (q also gets 512^-0.5)
  transpose_cvt<<<dim3(2, 16, 8), 256, 0, stream>>>(wq, Wqkv,                 512, 64, 512 * 64, 64 * 512, kScaleQ);
  transpose_cvt<<<dim3(2, 16, 8), 256, 0, stream>>>(wk, Wqkv + 512 * 512,     512, 64, 512 * 64, 64 * 512, kScale);
  transpose_cvt<<<dim3(2, 16, 8), 256, 0, stream>>>(wv, Wqkv + 2 * 512 * 512, 512, 64, 512 * 64, 64 * 512, kScale);
  transpose_cvt<<<dim3(16, 16, 1), 256, 0, stream>>>(w_proj, Wp, 512, 512, 0, 0, 1.f);
  transpose_cvt<<<dim3(64, 16, 1), 256, 0, stream>>>(w1, W1t, 512, 2048, 0, 0, 1.f);
  transpose_cvt<<<dim3(16, 64, 1), 256, 0, stream>>>(w2, W2t, 2048, 512, 0, 0, kScale);

  ln_kernel<<<2048, 256, 0, stream>>>(x, g1, be1, x_ln);
  gemm_bt<0><<<dim3(64, 12), 256, 0, stream>>>(x_ln, Wqkv, nullptr, nullptr, nullptr, nullptr,
                                               qb, kb, vb, 1536, 512);
  attn_kernel<<<dim3(32, 16), 256, 0, stream>>>(qb, kb, vb, attn);
  gemm_bt<1><<<dim3(64, 4), 256, 0, stream>>>(attn, Wp, b_proj, x, x1, nullptr,
                                              nullptr, nullptr, nullptr, 512, 512);
  ln_kernel<<<2048, 256, 0, stream>>>(x1, g2, be2, x1_ln);
  gemm_bt<2><<<dim3(64, 16), 256, 0, stream>>>(x1_ln, W1t, b1, nullptr, nullptr, hbuf,
                                               nullptr, nullptr, nullptr, 2048, 512);
  gemm_bt<3><<<dim3(64, 4), 256, 0, stream>>>(hbuf, W2t, b2, x1, outp, nullptr,
                                              nullptr, nullptr, nullptr, 512, 2048);
}